// Round 1
// baseline (302.724 us; speedup 1.0000x reference)
//
#include <hip/hip_runtime.h>

#define NCLS 19
#define HW (512 * 512)
#define NPIX (8 * HW)
#define NGRP (NPIX / 4)   // 524288 groups of 4 pixels

// ws layout (floats): [0]=sum_w [1]=sum_wnll [2]=focal_sum
//                     [3..21]=intersection [22..40]=prob_sums [41..59]=counts

__global__ __launch_bounds__(256)
void focal_dice_main(const float* __restrict__ logits,
                     const int*   __restrict__ target,
                     const float* __restrict__ cw,
                     const float* __restrict__ fa,
                     float*       __restrict__ ws)
{
    __shared__ float sh_cw[NCLS], sh_fa[NCLS];
    __shared__ float sh_inter[NCLS], sh_cnt[NCLS], sh_psum[NCLS];
    __shared__ float sh_scal[3];

    const int tid = threadIdx.x;
    if (tid < NCLS) {
        sh_cw[tid] = cw[tid];
        sh_fa[tid] = fa[tid];
        sh_inter[tid] = 0.f; sh_cnt[tid] = 0.f; sh_psum[tid] = 0.f;
    }
    if (tid < 3) sh_scal[tid] = 0.f;
    __syncthreads();

    const unsigned g   = blockIdx.x * 256u + (unsigned)tid;  // group id
    const unsigned b   = g >> 16;          // 65536 groups per image
    const unsigned hw4 = g & 65535u;

    const float4* lp = reinterpret_cast<const float4*>(logits)
                     + (size_t)b * (size_t)(NCLS * (HW / 4)) + hw4;
    const int4 t4 = reinterpret_cast<const int4*>(target)[g];

    // ---- load 19 classes x 4 pixels into registers ----
    float4 x[NCLS];
#pragma unroll
    for (int c = 0; c < NCLS; ++c)
        x[c] = lp[(size_t)c * (HW / 4)];

    // ---- max over classes (per pixel) ----
    float4 mx = x[0];
#pragma unroll
    for (int c = 1; c < NCLS; ++c) {
        mx.x = fmaxf(mx.x, x[c].x);
        mx.y = fmaxf(mx.y, x[c].y);
        mx.z = fmaxf(mx.z, x[c].z);
        mx.w = fmaxf(mx.w, x[c].w);
    }

    // ---- exp / sum; grab e_t for the target class on the fly ----
    float4 s  = make_float4(0.f, 0.f, 0.f, 0.f);
    float4 et = make_float4(0.f, 0.f, 0.f, 0.f);
#pragma unroll
    for (int c = 0; c < NCLS; ++c) {
        float4 e;
        e.x = __expf(x[c].x - mx.x);
        e.y = __expf(x[c].y - mx.y);
        e.z = __expf(x[c].z - mx.z);
        e.w = __expf(x[c].w - mx.w);
        s.x += e.x; s.y += e.y; s.z += e.z; s.w += e.w;
        if (t4.x == c) et.x = e.x;
        if (t4.y == c) et.y = e.y;
        if (t4.z == c) et.z = e.z;
        if (t4.w == c) et.w = e.w;
        x[c] = e;   // keep e_c for prob_sums pass
    }

    float4 rs;
    rs.x = __builtin_amdgcn_rcpf(s.x);
    rs.y = __builtin_amdgcn_rcpf(s.y);
    rs.z = __builtin_amdgcn_rcpf(s.z);
    rs.w = __builtin_amdgcn_rcpf(s.w);

    // ---- per-pixel pt / log_pt ----
    float4 pt, lpt;
    pt.x = et.x * rs.x;  pt.y = et.y * rs.y;
    pt.z = et.z * rs.z;  pt.w = et.w * rs.w;
    lpt.x = __logf(pt.x); lpt.y = __logf(pt.y);
    lpt.z = __logf(pt.z); lpt.w = __logf(pt.w);

    float4 ptc;  // clamped pt for focal factor (ref: max(exp(log_pt),1e-8))
    ptc.x = fmaxf(pt.x, 1e-8f); ptc.y = fmaxf(pt.y, 1e-8f);
    ptc.z = fmaxf(pt.z, 1e-8f); ptc.w = fmaxf(pt.w, 1e-8f);

    const float w0 = sh_cw[t4.x], w1 = sh_cw[t4.y], w2 = sh_cw[t4.z], w3 = sh_cw[t4.w];
    const float a0 = sh_fa[t4.x], a1 = sh_fa[t4.y], a2 = sh_fa[t4.z], a3 = sh_fa[t4.w];

    float v_sumw = w0 + w1 + w2 + w3;
    float v_wnll = -(w0 * lpt.x + w1 * lpt.y + w2 * lpt.z + w3 * lpt.w);
    const float o0 = 1.f - ptc.x, o1 = 1.f - ptc.y, o2 = 1.f - ptc.z, o3 = 1.f - ptc.w;
    float v_foc = -(a0 * o0 * o0 * lpt.x + a1 * o1 * o1 * lpt.y +
                    a2 * o2 * o2 * lpt.z + a3 * o3 * o3 * lpt.w);

    // ---- wave (64-lane) butterfly reduction ----
    auto wsum = [](float v) {
        v += __shfl_xor(v, 1);
        v += __shfl_xor(v, 2);
        v += __shfl_xor(v, 4);
        v += __shfl_xor(v, 8);
        v += __shfl_xor(v, 16);
        v += __shfl_xor(v, 32);
        return v;
    };

    const int lane = tid & 63;
    v_sumw = wsum(v_sumw);
    v_wnll = wsum(v_wnll);
    v_foc  = wsum(v_foc);
    if (lane == 0) {
        atomicAdd(&sh_scal[0], v_sumw);
        atomicAdd(&sh_scal[1], v_wnll);
        atomicAdd(&sh_scal[2], v_foc);
    }

    // ---- per-class prob sums: dot(e_c, 1/s) then wave-reduce ----
#pragma unroll
    for (int c = 0; c < NCLS; ++c) {
        float v = x[c].x * rs.x + x[c].y * rs.y + x[c].z * rs.z + x[c].w * rs.w;
        v = wsum(v);
        if (lane == c) atomicAdd(&sh_psum[c], v);
    }

    // ---- intersection & counts (target-scattered; LDS atomics) ----
    atomicAdd(&sh_inter[t4.x], pt.x);
    atomicAdd(&sh_inter[t4.y], pt.y);
    atomicAdd(&sh_inter[t4.z], pt.z);
    atomicAdd(&sh_inter[t4.w], pt.w);
    atomicAdd(&sh_cnt[t4.x], 1.f);
    atomicAdd(&sh_cnt[t4.y], 1.f);
    atomicAdd(&sh_cnt[t4.z], 1.f);
    atomicAdd(&sh_cnt[t4.w], 1.f);

    __syncthreads();

    // ---- one global atomic per class per block ----
    if (tid < NCLS) {
        atomicAdd(&ws[3 + tid],            sh_inter[tid]);
        atomicAdd(&ws[3 + NCLS + tid],     sh_psum[tid]);
        atomicAdd(&ws[3 + 2 * NCLS + tid], sh_cnt[tid]);
    } else if (tid >= 64 && tid < 67) {
        atomicAdd(&ws[tid - 64], sh_scal[tid - 64]);
    }
}

__global__ void focal_dice_final(const float* __restrict__ ws,
                                 const float* __restrict__ cw,
                                 float*       __restrict__ out)
{
    if (threadIdx.x == 0 && blockIdx.x == 0) {
        const float ce    = ws[1] / ws[0];
        const float focal = ws[2] * (1.f / (float)NPIX);
        float cwsum = 0.f;
        for (int c = 0; c < NCLS; ++c) cwsum += cw[c];
        const float inv = 1.f / fmaxf(cwsum, 1e-8f);
        float dsum = 0.f;
        for (int c = 0; c < NCLS; ++c) {
            const float I   = ws[3 + c];
            const float S   = ws[3 + NCLS + c];
            const float cnt = ws[3 + 2 * NCLS + c];
            const float dice = (2.f * I + 1.f) / (S + cnt + 1.f);
            dsum += dice * cw[c] * inv;
        }
        out[0] = 0.4f * ce + 0.3f * focal + 0.3f * (1.f - dsum);
    }
}

extern "C" void kernel_launch(void* const* d_in, const int* in_sizes, int n_in,
                              void* d_out, int out_size, void* d_ws, size_t ws_size,
                              hipStream_t stream)
{
    const float* logits = (const float*)d_in[0];
    const int*   target = (const int*)d_in[1];
    const float* cw     = (const float*)d_in[2];
    const float* fa     = (const float*)d_in[3];
    float* ws  = (float*)d_ws;
    float* out = (float*)d_out;

    hipMemsetAsync(d_ws, 0, (3 + 3 * NCLS) * sizeof(float), stream);
    focal_dice_main<<<NGRP / 256, 256, 0, stream>>>(logits, target, cw, fa, ws);
    focal_dice_final<<<1, 64, 0, stream>>>(ws, cw, out);
}

// Round 2
// 250.124 us; speedup vs baseline: 1.2103x; 1.2103x over previous
//
#include <hip/hip_runtime.h>

#define NCLS 19
#define HW (512 * 512)
#define NPIX (8 * HW)
#define NGRP (NPIX / 4)          // 524288 groups of 4 pixels
#define BLOCKS 512
#define THREADS 256
#define TOT (BLOCKS * THREADS)   // 131072 threads
#define GPT (NGRP / TOT)         // 4 groups per thread

// ws layout (floats): [0]=sum_wnll [1]=focal_sum
//                     [2..20]=intersection [21..39]=prob_sums [40..58]=counts

__global__ __launch_bounds__(THREADS)
void focal_dice_main(const float* __restrict__ logits,
                     const int*   __restrict__ target,
                     const float* __restrict__ cw,
                     const float* __restrict__ fa,
                     float*       __restrict__ ws)
{
    __shared__ float sh_cw[NCLS], sh_fa[NCLS];
    __shared__ float sh_inter[NCLS], sh_cnt[NCLS], sh_psum[NCLS];
    __shared__ float sh_scal[2];

    const int tid = threadIdx.x;
    if (tid < NCLS) {
        sh_cw[tid] = cw[tid];
        sh_fa[tid] = fa[tid];
        sh_inter[tid] = 0.f; sh_cnt[tid] = 0.f; sh_psum[tid] = 0.f;
    }
    if (tid < 2) sh_scal[tid] = 0.f;
    __syncthreads();

    const unsigned gid = blockIdx.x * (unsigned)THREADS + (unsigned)tid;

    // thread-persistent accumulators
    float psum[NCLS];
#pragma unroll
    for (int c = 0; c < NCLS; ++c) psum[c] = 0.f;
    float v_wnll = 0.f, v_foc = 0.f;

    for (int k = 0; k < GPT; ++k) {
        const unsigned g   = gid + (unsigned)k * TOT;   // group id
        const unsigned b   = g >> 16;                   // 65536 groups per image
        const unsigned hw4 = g & 65535u;

        const float4* lp = reinterpret_cast<const float4*>(logits)
                         + (size_t)b * (size_t)(NCLS * (HW / 4)) + hw4;
        const int4 t4 = reinterpret_cast<const int4*>(target)[g];

        // ---- load 19 classes x 4 pixels ----
        float4 x[NCLS];
#pragma unroll
        for (int c = 0; c < NCLS; ++c)
            x[c] = lp[(size_t)c * (HW / 4)];

        // ---- max over classes (per pixel) ----
        float4 mx = x[0];
#pragma unroll
        for (int c = 1; c < NCLS; ++c) {
            mx.x = fmaxf(mx.x, x[c].x);
            mx.y = fmaxf(mx.y, x[c].y);
            mx.z = fmaxf(mx.z, x[c].z);
            mx.w = fmaxf(mx.w, x[c].w);
        }

        // ---- exp / sum; grab e_t on the fly ----
        float4 s  = make_float4(0.f, 0.f, 0.f, 0.f);
        float4 et = make_float4(0.f, 0.f, 0.f, 0.f);
#pragma unroll
        for (int c = 0; c < NCLS; ++c) {
            float4 e;
            e.x = __expf(x[c].x - mx.x);
            e.y = __expf(x[c].y - mx.y);
            e.z = __expf(x[c].z - mx.z);
            e.w = __expf(x[c].w - mx.w);
            s.x += e.x; s.y += e.y; s.z += e.z; s.w += e.w;
            if (t4.x == c) et.x = e.x;
            if (t4.y == c) et.y = e.y;
            if (t4.z == c) et.z = e.z;
            if (t4.w == c) et.w = e.w;
            x[c] = e;   // keep e_c for prob_sums accumulation
        }

        float4 rs;
        rs.x = __builtin_amdgcn_rcpf(s.x);
        rs.y = __builtin_amdgcn_rcpf(s.y);
        rs.z = __builtin_amdgcn_rcpf(s.z);
        rs.w = __builtin_amdgcn_rcpf(s.w);

        // ---- per-pixel pt / log_pt ----
        float4 pt, lpt;
        pt.x = et.x * rs.x;  pt.y = et.y * rs.y;
        pt.z = et.z * rs.z;  pt.w = et.w * rs.w;
        lpt.x = __logf(pt.x); lpt.y = __logf(pt.y);
        lpt.z = __logf(pt.z); lpt.w = __logf(pt.w);

        float4 ptc;  // clamped pt for focal factor
        ptc.x = fmaxf(pt.x, 1e-8f); ptc.y = fmaxf(pt.y, 1e-8f);
        ptc.z = fmaxf(pt.z, 1e-8f); ptc.w = fmaxf(pt.w, 1e-8f);

        const float w0 = sh_cw[t4.x], w1 = sh_cw[t4.y], w2 = sh_cw[t4.z], w3 = sh_cw[t4.w];
        const float a0 = sh_fa[t4.x], a1 = sh_fa[t4.y], a2 = sh_fa[t4.z], a3 = sh_fa[t4.w];

        v_wnll -= (w0 * lpt.x + w1 * lpt.y + w2 * lpt.z + w3 * lpt.w);
        const float o0 = 1.f - ptc.x, o1 = 1.f - ptc.y, o2 = 1.f - ptc.z, o3 = 1.f - ptc.w;
        v_foc -= (a0 * o0 * o0 * lpt.x + a1 * o1 * o1 * lpt.y +
                  a2 * o2 * o2 * lpt.z + a3 * o3 * o3 * lpt.w);

        // ---- prob_sums into registers (amortized reduction) ----
#pragma unroll
        for (int c = 0; c < NCLS; ++c)
            psum[c] += x[c].x * rs.x + x[c].y * rs.y + x[c].z * rs.z + x[c].w * rs.w;

        // ---- intersection & counts: LDS atomics (scattered by target) ----
        atomicAdd(&sh_inter[t4.x], pt.x);
        atomicAdd(&sh_inter[t4.y], pt.y);
        atomicAdd(&sh_inter[t4.z], pt.z);
        atomicAdd(&sh_inter[t4.w], pt.w);
        atomicAdd(&sh_cnt[t4.x], 1.f);
        atomicAdd(&sh_cnt[t4.y], 1.f);
        atomicAdd(&sh_cnt[t4.z], 1.f);
        atomicAdd(&sh_cnt[t4.w], 1.f);
    }

    // ---- once-per-thread wave reductions ----
    auto wsum = [](float v) {
        v += __shfl_xor(v, 1);
        v += __shfl_xor(v, 2);
        v += __shfl_xor(v, 4);
        v += __shfl_xor(v, 8);
        v += __shfl_xor(v, 16);
        v += __shfl_xor(v, 32);
        return v;
    };

    const int lane = tid & 63;
    v_wnll = wsum(v_wnll);
    v_foc  = wsum(v_foc);
    if (lane == 0) {
        atomicAdd(&sh_scal[0], v_wnll);
        atomicAdd(&sh_scal[1], v_foc);
    }
#pragma unroll
    for (int c = 0; c < NCLS; ++c) {
        float v = wsum(psum[c]);
        if (lane == c) atomicAdd(&sh_psum[c], v);
    }

    __syncthreads();

    // ---- one global atomic per class per block ----
    if (tid < NCLS) {
        atomicAdd(&ws[2 + tid],            sh_inter[tid]);
        atomicAdd(&ws[2 + NCLS + tid],     sh_psum[tid]);
        atomicAdd(&ws[2 + 2 * NCLS + tid], sh_cnt[tid]);
    } else if (tid >= 64 && tid < 66) {
        atomicAdd(&ws[tid - 64], sh_scal[tid - 64]);
    }
}

__global__ void focal_dice_final(const float* __restrict__ ws,
                                 const float* __restrict__ cw,
                                 float*       __restrict__ out)
{
    if (threadIdx.x == 0 && blockIdx.x == 0) {
        float sum_w = 0.f;
        for (int c = 0; c < NCLS; ++c) sum_w += cw[c] * ws[2 + 2 * NCLS + c];
        const float ce    = ws[0] / sum_w;
        const float focal = ws[1] * (1.f / (float)NPIX);
        float cwsum = 0.f;
        for (int c = 0; c < NCLS; ++c) cwsum += cw[c];
        const float inv = 1.f / fmaxf(cwsum, 1e-8f);
        float dsum = 0.f;
        for (int c = 0; c < NCLS; ++c) {
            const float I   = ws[2 + c];
            const float S   = ws[2 + NCLS + c];
            const float cnt = ws[2 + 2 * NCLS + c];
            const float dice = (2.f * I + 1.f) / (S + cnt + 1.f);
            dsum += dice * cw[c] * inv;
        }
        out[0] = 0.4f * ce + 0.3f * focal + 0.3f * (1.f - dsum);
    }
}

extern "C" void kernel_launch(void* const* d_in, const int* in_sizes, int n_in,
                              void* d_out, int out_size, void* d_ws, size_t ws_size,
                              hipStream_t stream)
{
    const float* logits = (const float*)d_in[0];
    const int*   target = (const int*)d_in[1];
    const float* cw     = (const float*)d_in[2];
    const float* fa     = (const float*)d_in[3];
    float* ws  = (float*)d_ws;
    float* out = (float*)d_out;

    hipMemsetAsync(d_ws, 0, (2 + 3 * NCLS) * sizeof(float), stream);
    focal_dice_main<<<BLOCKS, THREADS, 0, stream>>>(logits, target, cw, fa, ws);
    focal_dice_final<<<1, 64, 0, stream>>>(ws, cw, out);
}